// Round 6
// baseline (15102.991 us; speedup 1.0000x reference)
//
#include <hip/hip_runtime.h>
#include <stdint.h>
#include <stddef.h>

#define B_  64
#define T_  256
#define H_  1024
#define AS_ 128
#define L_  3

typedef __attribute__((ext_vector_type(8))) short bf16x8;
typedef __attribute__((ext_vector_type(4))) float f32x4;
typedef __attribute__((ext_vector_type(4))) unsigned u32x4;

__device__ __forceinline__ unsigned short f2bf(float f) {
  union { float f; unsigned u; } x; x.f = f;
  unsigned r = x.u + 0x7fffu + ((x.u >> 16) & 1u);   // RNE
  return (unsigned short)(r >> 16);
}
__device__ __forceinline__ float bf2f(unsigned short s) {
  union { unsigned u; float f; } x; x.u = ((unsigned)s) << 16; return x.f;
}
__device__ __forceinline__ float sigmf(float x) { return 1.0f / (1.0f + __expf(-x)); }
__device__ __forceinline__ float tanh_f(float x) {
  x = fminf(fmaxf(x, -15.0f), 15.0f);
  float e = __expf(2.0f * x);
  return (e - 1.0f) / (e + 1.0f);
}

// ---- device-coherent (MALL) accessors: relaxed agent atomics — proven R2/R5 ----
__device__ __forceinline__ unsigned long long ld_u64_cc(const void* p) {
  return __hip_atomic_load((const unsigned long long*)p, __ATOMIC_RELAXED, __HIP_MEMORY_SCOPE_AGENT);
}
__device__ __forceinline__ void st_u32_cc(unsigned* p, unsigned v) {
  __hip_atomic_store(p, v, __ATOMIC_RELAXED, __HIP_MEMORY_SCOPE_AGENT);
}

// ---------------- tiny utility kernels ----------------

__global__ void k_wt_i2h(const float* __restrict__ W, const float* __restrict__ b,
                         unsigned short* __restrict__ Wt) {
  int id = blockIdx.x * 256 + threadIdx.x;
  if (id >= AS_ * H_) return;
  int a = id >> 10, h = id & 1023;
  Wt[id] = f2bf(W[h * AS_ + a] + b[h]);
}

__global__ void k_f2b(const float* __restrict__ s, unsigned short* __restrict__ d, int n) {
  int i = blockIdx.x * 256 + threadIdx.x;
  if (i < n) d[i] = f2bf(s[i]);
}

__global__ void k_bias(const float* __restrict__ bi, const float* __restrict__ bh,
                       float* __restrict__ o, int n) {
  int i = blockIdx.x * 256 + threadIdx.x;
  if (i < n) o[i] = bi[i] + bh[i];
}

__global__ __launch_bounds__(128) void k_gather(const float* __restrict__ seq,
                                                const unsigned short* __restrict__ Wt,
                                                unsigned short* __restrict__ xbf) {
  __shared__ int sidx;
  const int bt = blockIdx.x, tid = threadIdx.x;
  if (seq[(size_t)bt * AS_ + tid] > 0.5f) sidx = tid;
  __syncthreads();
  const uint4* s = (const uint4*)(Wt + (size_t)sidx * H_);
  uint4* d = (uint4*)(xbf + (size_t)bt * H_);
  d[tid] = s[tid];
}

// ---------------- MFMA GEMM (unchanged, proven) ----------------

__device__ __forceinline__ void gld16(const void* g, void* l) {
  __builtin_amdgcn_global_load_lds((const __attribute__((address_space(1))) unsigned int*)g,
                                   (__attribute__((address_space(3))) unsigned int*)l,
                                   16, 0, 0);
}

template <int OUT_BF16>
__global__ __launch_bounds__(256) void k_gemm(const unsigned short* __restrict__ A,
                                              const unsigned short* __restrict__ Bm,
                                              const float* __restrict__ bias,
                                              void* __restrict__ Cout,
                                              int M, int N, int K) {
  __shared__ __align__(16) unsigned short As[128 * 32];
  __shared__ __align__(16) unsigned short Bs[128 * 32];
  const int tid = threadIdx.x, lane = tid & 63, wv = tid >> 6;
  const int m0 = blockIdx.x * 128, n0 = blockIdx.y * 128;
  const int wr = wv >> 1, wc = wv & 1;
  const int kg = lane >> 4, li = lane & 15;
  f32x4 acc[4][4] = {};

  for (int k0 = 0; k0 < K; k0 += 32) {
    for (int i = 0; i < 2; ++i) {
      int c0 = i * 256 + wv * 64;
      int cid = c0 + lane;
      int row = cid >> 2, lc = cid & 3;
      int sc = lc ^ ((row >> 1) & 3);
      gld16(A + (size_t)(m0 + row) * K + k0 + sc * 8, (char*)As + (size_t)c0 * 16);
      gld16(Bm + (size_t)(n0 + row) * K + k0 + sc * 8, (char*)Bs + (size_t)c0 * 16);
    }
    __syncthreads();
    bf16x8 af[4], bfm[4];
#pragma unroll
    for (int mi = 0; mi < 4; ++mi) {
      int row = wr * 64 + mi * 16 + li;
      int pc = kg ^ ((row >> 1) & 3);
      af[mi] = *(const bf16x8*)((const char*)As + row * 64 + pc * 16);
    }
#pragma unroll
    for (int ni = 0; ni < 4; ++ni) {
      int row = wc * 64 + ni * 16 + li;
      int pc = kg ^ ((row >> 1) & 3);
      bfm[ni] = *(const bf16x8*)((const char*)Bs + row * 64 + pc * 16);
    }
#pragma unroll
    for (int mi = 0; mi < 4; ++mi)
#pragma unroll
      for (int ni = 0; ni < 4; ++ni)
        acc[mi][ni] = __builtin_amdgcn_mfma_f32_16x16x32_bf16(af[mi], bfm[ni], acc[mi][ni], 0, 0, 0);
    __syncthreads();
  }

#pragma unroll
  for (int mi = 0; mi < 4; ++mi)
#pragma unroll
    for (int ni = 0; ni < 4; ++ni)
#pragma unroll
      for (int r = 0; r < 4; ++r) {
        int row = m0 + wr * 64 + mi * 16 + kg * 4 + r;
        int col = n0 + wc * 64 + ni * 16 + li;
        float v = acc[mi][ni][r] + bias[col];
        if (OUT_BF16) ((unsigned short*)Cout)[(size_t)row * N + col] = f2bf(v);
        else          ((float*)Cout)[(size_t)row * N + col] = v;
      }
}

// ---------------- persistent LSTM scan: barrier-free epoch-tagged dataflow ----------------
// h element = u32: (tag << 16) | bf16(h).  tag = (layer<<10) + step + 1.
// Double parity buffers h_ep[2][B][H]. Producers: ONE bypass u32 store per element,
// no drain, no flags. Consumers: poll-with-data (reload own 256B slice until all
// tags match) — data is in registers when the poll exits. Overwrite safety: a wg
// writes epoch t+2 (parity p) only after observing ALL epoch t+1 words, whose
// values data-depend on their producers having fully read epoch t (parity p).
// Max skew self-throttles to 1 step. Poison 0xAAAA never matches a valid tag;
// replays are bit-deterministic so stale-slot races are value-identical (benign).

__global__ __launch_bounds__(256, 1) void k_scan(
    const unsigned short* __restrict__ xg,    // [B*T][4H] bf16 (bias folded)
    const float* __restrict__ Whh,            // [4H][H] f32
    unsigned* __restrict__ h_ep,              // [2][B][H] u32 (MALL)
    unsigned short* __restrict__ out_seq,     // [B*T][H] bf16 or null
    float* __restrict__ hT, float* __restrict__ cT,
    const float* __restrict__ h0, const float* __restrict__ c0,
    int ltag) {                               // layer<<10
  __shared__ __align__(16) unsigned short Wlds[4 * 16 * 1024];  // 128 KB
  __shared__ __align__(16) unsigned short Hs[16 * 1024];        // 32 KB; gx aliased
  float* gx = (float*)(void*)Hs;
  const int tid = threadIdx.x, lane = tid & 63, wave = tid >> 6;
  const int wg = blockIdx.x, gb = wg >> 6, ug = wg & 63;
  const int li = lane & 15, kq = lane >> 4;

  const int bm = gb * 16 + kq * 4 + wave;     // this thread's produced (batch,unit)
  const int uu = ug * 16 + li;

  // ---- publish h0 chunk FIRST (overlaps weight staging of all wgs)
  st_u32_cc(&h_ep[((size_t)1 * B_ + bm) * H_ + uu],
            ((unsigned)(ltag + 1) << 16) | f2bf(h0[(size_t)bm * H_ + uu]));

  // ---- W_hh slice -> LDS bf16, swizzled: byte = (wave*16+u)*2048 + (2k ^ ((u&7)<<4))
  for (int it = 0; it < 64; ++it) {
    int idx = it * 256 + lane * 4;
    int u = idx >> 10, k = idx & 1023;
    const float4 w = *(const float4*)&Whh[((size_t)(wave * H_ + ug * 16 + u)) * H_ + k];
    ushort4 p; p.x = f2bf(w.x); p.y = f2bf(w.y); p.z = f2bf(w.z); p.w = f2bf(w.w);
    *(ushort4*)((char*)Wlds + (size_t)(wave * 16 + u) * 2048 + ((2 * k) ^ ((u & 7) << 4))) = p;
  }
  float c_st = c0[(size_t)bm * H_ + uu];
  __syncthreads();                            // Wlds ready

  const char* bbase = (const char*)Wlds + (size_t)(wave * 16 + li) * 2048;
  const char* abase = (const char*)Hs + (size_t)li * 2048;
  const int lxor = (li & 7) << 4;
  const int srow_r = tid >> 4, sseg = tid & 15;
  const int sswz = (srow_r & 7) << 4;

  for (int t = 0; t < T_; ++t) {
    const unsigned etag = (unsigned)(ltag + t + 1);

    // xg for this step (cached loads, issued before the poll to overlap HBM latency)
    float xv[4];
#pragma unroll
    for (int r = 0; r < 4; ++r)
      xv[r] = bf2f(xg[((size_t)(gb * 16 + kq * 4 + r) * T_ + t) * (4 * H_) + (size_t)wave * H_ + uu]);

    // ---- poll-with-data: thread owns row (gb*16+srow_r), units [sseg*64, +64)
    unsigned pk[32];
    {
      const char* src = (const char*)h_ep +
          (((size_t)((t & 1) ^ 1) * B_ + gb * 16 + srow_r) * H_) * 4 + (size_t)sseg * 256;
      for (;;) {
        unsigned long long w[32];
#pragma unroll
        for (int m = 0; m < 32; ++m) w[m] = ld_u64_cc(src + m * 8);
        bool ok = true;
#pragma unroll
        for (int m = 0; m < 32; ++m) {
          unsigned lo = (unsigned)w[m], hi = (unsigned)(w[m] >> 32);
          ok &= ((lo >> 16) == etag) & ((hi >> 16) == etag);
          pk[m] = (lo & 0xffffu) | (hi << 16);
        }
        if (ok) break;
        __builtin_amdgcn_s_sleep(1);
      }
    }
    // ---- write slice to LDS (swizzled), rotated store order for bank spread
    {
      char* drow = (char*)Hs + (size_t)srow_r * 2048;
#pragma unroll
      for (int m = 0; m < 8; ++m) {
        int cm = (m + sseg) & 7;
        *(u32x4*)(drow + ((sseg * 128 + cm * 16) ^ sswz)) = *(u32x4*)&pk[4 * cm];
      }
    }
    __syncthreads();

    // ---- gate MFMA chain: wave = gate, dual accumulators
    f32x4 acc0 = {0.f, 0.f, 0.f, 0.f}, acc1 = {0.f, 0.f, 0.f, 0.f};
#pragma unroll
    for (int ks = 0; ks < 32; ks += 2) {
      bf16x8 a0 = *(const bf16x8*)(abase + ((ks * 64 + kq * 16) ^ lxor));
      bf16x8 b0 = *(const bf16x8*)(bbase + ((ks * 64 + kq * 16) ^ lxor));
      acc0 = __builtin_amdgcn_mfma_f32_16x16x32_bf16(a0, b0, acc0, 0, 0, 0);
      bf16x8 a1 = *(const bf16x8*)(abase + (((ks + 1) * 64 + kq * 16) ^ lxor));
      bf16x8 b1 = *(const bf16x8*)(bbase + (((ks + 1) * 64 + kq * 16) ^ lxor));
      acc1 = __builtin_amdgcn_mfma_f32_16x16x32_bf16(a1, b1, acc1, 0, 0, 0);
    }
    __syncthreads();                          // Hs reads done before gx overwrites

#pragma unroll
    for (int r = 0; r < 4; ++r)
      gx[wave * 320 + lane * 5 + r] = acc0[r] + acc1[r] + xv[r];
    __syncthreads();

    // ---- cell update: all 4 waves, r = wave; publish ONE tagged u32, no drain
    {
      float gi = gx[0 * 320 + lane * 5 + wave];
      float gf = gx[1 * 320 + lane * 5 + wave];
      float gg = gx[2 * 320 + lane * 5 + wave];
      float go = gx[3 * 320 + lane * 5 + wave];
      float ci = sigmf(gf) * c_st + sigmf(gi) * tanh_f(gg);
      c_st = ci;
      float h = sigmf(go) * tanh_f(ci);
      unsigned short hbf = f2bf(h);
      st_u32_cc(&h_ep[((size_t)(t & 1) * B_ + bm) * H_ + uu],
                ((etag + 1u) << 16) | (unsigned)hbf);
      if (out_seq) out_seq[((size_t)bm * T_ + t) * H_ + uu] = hbf;
      if (t == T_ - 1) {
        hT[(size_t)bm * H_ + uu] = h;
        cT[(size_t)bm * H_ + uu] = ci;
      }
    }
    __syncthreads();                          // gx consumed before next stage reuses Hs
  }
}

// ---------------- launcher ----------------

extern "C" void kernel_launch(void* const* d_in, const int* in_sizes, int n_in,
                              void* d_out, int out_size, void* d_ws, size_t ws_size,
                              hipStream_t stream) {
  const float* seq  = (const float*)d_in[0];
  const float* Wi2h = (const float*)d_in[1];
  const float* bi2h = (const float*)d_in[2];
  const float* Wih  = (const float*)d_in[3];
  const float* Whh  = (const float*)d_in[4];
  const float* bih  = (const float*)d_in[5];
  const float* bhh  = (const float*)d_in[6];
  const float* Wh2o = (const float*)d_in[7];
  const float* bh2o = (const float*)d_in[8];
  const float* h0   = (const float*)d_in[9];
  const float* c0   = (const float*)d_in[10];
  float* outF = (float*)d_out;

  size_t off = 0;
  auto nb = [&](size_t bytes) { size_t r = off; off += (bytes + 255) & ~(size_t)255; return r; };
  unsigned short* xbf   = (unsigned short*)((char*)d_ws + nb((size_t)B_ * T_ * H_ * 2));
  unsigned short* seqA  = (unsigned short*)((char*)d_ws + nb((size_t)B_ * T_ * H_ * 2));
  unsigned short* xg    = (unsigned short*)((char*)d_ws + nb((size_t)B_ * T_ * 4 * H_ * 2));
  unsigned short* Wihb  = (unsigned short*)((char*)d_ws + nb((size_t)L_ * 4 * H_ * H_ * 2));
  unsigned short* Wh2ob = (unsigned short*)((char*)d_ws + nb((size_t)AS_ * H_ * 2));
  unsigned short* Wt    = (unsigned short*)((char*)d_ws + nb((size_t)AS_ * H_ * 2));
  float*          bsum  = (float*)((char*)d_ws + nb((size_t)L_ * 4 * H_ * 4));
  unsigned*       h_ep  = (unsigned*)((char*)d_ws + nb((size_t)2 * B_ * H_ * 4));  // 512KB
  (void)ws_size; (void)in_sizes; (void)n_in; (void)out_size;

  const int WLAYER = 4 * H_ * H_;

  k_wt_i2h<<<(AS_ * H_ + 255) / 256, 256, 0, stream>>>(Wi2h, bi2h, Wt);
  k_f2b<<<(L_ * WLAYER + 255) / 256, 256, 0, stream>>>(Wih, Wihb, L_ * WLAYER);
  k_f2b<<<(AS_ * H_ + 255) / 256, 256, 0, stream>>>(Wh2o, Wh2ob, AS_ * H_);
  k_bias<<<(L_ * 4 * H_ + 255) / 256, 256, 0, stream>>>(bih, bhh, bsum, L_ * 4 * H_);
  k_gather<<<B_ * T_, 128, 0, stream>>>(seq, Wt, xbf);

  // out = x @ W_h2O^T + b  (faithful to reference bug: uses x, not LSTM output)
  k_gemm<0><<<dim3(B_ * T_ / 128, AS_ / 128), 256, 0, stream>>>(
      xbf, Wh2ob, bh2o, (void*)outF, B_ * T_, AS_, H_);

  float* hT_base = outF + (size_t)B_ * T_ * AS_;
  float* cT_base = hT_base + (size_t)L_ * B_ * H_;

  for (int l = 0; l < L_; ++l) {
    const unsigned short* Ain = (l == 0) ? xbf : (l == 1) ? seqA : xbf;
    unsigned short* oseq = (l == 0) ? seqA : (l == 1) ? xbf : nullptr;
    k_gemm<1><<<dim3(B_ * T_ / 128, 4 * H_ / 128), 256, 0, stream>>>(
        Ain, Wihb + (size_t)l * WLAYER, bsum + (size_t)l * 4 * H_, (void*)xg,
        B_ * T_, 4 * H_, H_);
    k_scan<<<256, 256, 0, stream>>>(
        xg, Whh + (size_t)l * WLAYER, h_ep, oseq,
        hT_base + (size_t)l * B_ * H_, cT_base + (size_t)l * B_ * H_,
        h0 + (size_t)l * B_ * H_, c0 + (size_t)l * B_ * H_,
        l << 10);
  }
}

// Round 7
// 10816.349 us; speedup vs baseline: 1.3963x; 1.3963x over previous
//
#include <hip/hip_runtime.h>
#include <stdint.h>
#include <stddef.h>

#define B_  64
#define T_  256
#define H_  1024
#define AS_ 128
#define L_  3

typedef __attribute__((ext_vector_type(8))) short bf16x8;
typedef __attribute__((ext_vector_type(4))) float f32x4;

__device__ __forceinline__ unsigned short f2bf(float f) {
  union { float f; unsigned u; } x; x.f = f;
  unsigned r = x.u + 0x7fffu + ((x.u >> 16) & 1u);   // RNE
  return (unsigned short)(r >> 16);
}
__device__ __forceinline__ float bf2f(unsigned short s) {
  union { unsigned u; float f; } x; x.u = ((unsigned)s) << 16; return x.f;
}
__device__ __forceinline__ float sigmf(float x) { return 1.0f / (1.0f + __expf(-x)); }
__device__ __forceinline__ float tanh_f(float x) {
  x = fminf(fmaxf(x, -15.0f), 15.0f);
  float e = __expf(2.0f * x);
  return (e - 1.0f) / (e + 1.0f);
}

// ---- device-coherent (MALL) accessors: relaxed agent atomics — proven R2/R5 ----
__device__ __forceinline__ unsigned long long ld_u64_cc(const void* p) {
  return __hip_atomic_load((const unsigned long long*)p, __ATOMIC_RELAXED, __HIP_MEMORY_SCOPE_AGENT);
}
__device__ __forceinline__ void st_u32_cc(unsigned* p, unsigned v) {
  __hip_atomic_store(p, v, __ATOMIC_RELAXED, __HIP_MEMORY_SCOPE_AGENT);
}

// ---------------- tiny utility kernels ----------------

__global__ void k_wt_i2h(const float* __restrict__ W, const float* __restrict__ b,
                         unsigned short* __restrict__ Wt) {
  int id = blockIdx.x * 256 + threadIdx.x;
  if (id >= AS_ * H_) return;
  int a = id >> 10, h = id & 1023;
  Wt[id] = f2bf(W[h * AS_ + a] + b[h]);
}

__global__ void k_f2b(const float* __restrict__ s, unsigned short* __restrict__ d, int n) {
  int i = blockIdx.x * 256 + threadIdx.x;
  if (i < n) d[i] = f2bf(s[i]);
}

__global__ void k_bias(const float* __restrict__ bi, const float* __restrict__ bh,
                       float* __restrict__ o, int n) {
  int i = blockIdx.x * 256 + threadIdx.x;
  if (i < n) o[i] = bi[i] + bh[i];
}

__global__ __launch_bounds__(128) void k_gather(const float* __restrict__ seq,
                                                const unsigned short* __restrict__ Wt,
                                                unsigned short* __restrict__ xbf) {
  __shared__ int sidx;
  const int bt = blockIdx.x, tid = threadIdx.x;
  if (seq[(size_t)bt * AS_ + tid] > 0.5f) sidx = tid;
  __syncthreads();
  const uint4* s = (const uint4*)(Wt + (size_t)sidx * H_);
  uint4* d = (uint4*)(xbf + (size_t)bt * H_);
  d[tid] = s[tid];
}

// ---------------- MFMA GEMM (unchanged, proven) ----------------

__device__ __forceinline__ void gld16(const void* g, void* l) {
  __builtin_amdgcn_global_load_lds((const __attribute__((address_space(1))) unsigned int*)g,
                                   (__attribute__((address_space(3))) unsigned int*)l,
                                   16, 0, 0);
}

template <int OUT_BF16>
__global__ __launch_bounds__(256) void k_gemm(const unsigned short* __restrict__ A,
                                              const unsigned short* __restrict__ Bm,
                                              const float* __restrict__ bias,
                                              void* __restrict__ Cout,
                                              int M, int N, int K) {
  __shared__ __align__(16) unsigned short As[128 * 32];
  __shared__ __align__(16) unsigned short Bs[128 * 32];
  const int tid = threadIdx.x, lane = tid & 63, wv = tid >> 6;
  const int m0 = blockIdx.x * 128, n0 = blockIdx.y * 128;
  const int wr = wv >> 1, wc = wv & 1;
  const int kg = lane >> 4, li = lane & 15;
  f32x4 acc[4][4] = {};

  for (int k0 = 0; k0 < K; k0 += 32) {
    for (int i = 0; i < 2; ++i) {
      int c0 = i * 256 + wv * 64;
      int cid = c0 + lane;
      int row = cid >> 2, lc = cid & 3;
      int sc = lc ^ ((row >> 1) & 3);
      gld16(A + (size_t)(m0 + row) * K + k0 + sc * 8, (char*)As + (size_t)c0 * 16);
      gld16(Bm + (size_t)(n0 + row) * K + k0 + sc * 8, (char*)Bs + (size_t)c0 * 16);
    }
    __syncthreads();
    bf16x8 af[4], bfm[4];
#pragma unroll
    for (int mi = 0; mi < 4; ++mi) {
      int row = wr * 64 + mi * 16 + li;
      int pc = kg ^ ((row >> 1) & 3);
      af[mi] = *(const bf16x8*)((const char*)As + row * 64 + pc * 16);
    }
#pragma unroll
    for (int ni = 0; ni < 4; ++ni) {
      int row = wc * 64 + ni * 16 + li;
      int pc = kg ^ ((row >> 1) & 3);
      bfm[ni] = *(const bf16x8*)((const char*)Bs + row * 64 + pc * 16);
    }
#pragma unroll
    for (int mi = 0; mi < 4; ++mi)
#pragma unroll
      for (int ni = 0; ni < 4; ++ni)
        acc[mi][ni] = __builtin_amdgcn_mfma_f32_16x16x32_bf16(af[mi], bfm[ni], acc[mi][ni], 0, 0, 0);
    __syncthreads();
  }

#pragma unroll
  for (int mi = 0; mi < 4; ++mi)
#pragma unroll
    for (int ni = 0; ni < 4; ++ni)
#pragma unroll
      for (int r = 0; r < 4; ++r) {
        int row = m0 + wr * 64 + mi * 16 + kg * 4 + r;
        int col = n0 + wc * 64 + ni * 16 + li;
        float v = acc[mi][ni][r] + bias[col];
        if (OUT_BF16) ((unsigned short*)Cout)[(size_t)row * N + col] = f2bf(v);
        else          ((float*)Cout)[(size_t)row * N + col] = v;
      }
}

// ---------------- persistent LSTM scan: tagged dataflow + operand-swapped MFMA ----------------
// h word = (tag<<16)|bf16, tag = (l<<10)+t+2 written at step t (parity t&1); h0 = tag (l<<10)+1
// at parity 1. Producer: one bypass u32 store + vmcnt(0) drain (prompt visibility — R6 lesson).
// Consumer: speculative 32x u64 bulk read (all issued before checks, const indices — no scratch),
// tag-validate, selective per-word re-spin. No flags, no rendezvous; skew self-throttles to 1 step
// (write t+2 only after observing all t+1, which data-depend on t consumed).
// MFMA operand swap: A = Wlds row (u_local*4+gate) so C row = kq*4+r gives u_local=kq, gate=r:
// each lane holds all 4 gates of its (batch=li, unit=ug*16+wave*4+kq) — update is lane-local,
// gx exchange deleted, 2 barriers/step.

__global__ __launch_bounds__(256, 1) void k_scan(
    const unsigned short* __restrict__ xg,    // [B*T][4H] bf16 (bias folded)
    const float* __restrict__ Whh,            // [4H][H] f32
    unsigned* __restrict__ h_ep,              // [2][B][H] u32 tagged (MALL)
    unsigned short* __restrict__ out_seq,     // [B*T][H] bf16 or null
    float* __restrict__ hT, float* __restrict__ cT,
    const float* __restrict__ h0, const float* __restrict__ c0,
    int ltag) {
  __shared__ __align__(16) unsigned short Wlds[64 * 1024];   // 128 KB, row rix = wave*16+li
  __shared__ __align__(16) unsigned short Hs[16 * 1024];     // 32 KB, row = batch_local
  const int tid = threadIdx.x, lane = tid & 63, wave = tid >> 6;
  const int wg = blockIdx.x, gb = wg >> 6, ug = wg & 63;
  const int li = lane & 15, kq = lane >> 4;
  const int b  = gb * 16 + li;              // this thread's batch
  const int u  = ug * 16 + wave * 4 + kq;   // this thread's unit

  // ---- publish h0 first (overlaps weight staging everywhere)
  st_u32_cc(&h_ep[((size_t)1 * B_ + b) * H_ + u],
            ((unsigned)(ltag + 1) << 16) | f2bf(h0[(size_t)b * H_ + u]));

  // ---- weights -> LDS, row rix holds W_orig[gate=rix&3][unit=ug*16+(rix>>4)*4+((rix>>2)&3)]
  for (int it = 0; it < 64; ++it) {
    const float4 v4 = *(const float4*)&Whh[
        ((size_t)(it & 3) * H_ + ug * 16 + (it >> 4) * 4 + ((it >> 2) & 3)) * H_ + tid * 4];
    ushort4 p; p.x = f2bf(v4.x); p.y = f2bf(v4.y); p.z = f2bf(v4.z); p.w = f2bf(v4.w);
    *(ushort4*)((char*)Wlds + (size_t)it * 2048 + ((tid * 8) ^ ((it & 7) << 4))) = p;
  }
  float c_st = c0[(size_t)b * H_ + u];
  __syncthreads();

  const int sb = tid >> 4, seg = tid & 15;     // stage role: batch row sb, 64-unit segment seg
  const int sswz = (sb & 7) << 4;
  char* drow = (char*)Hs + (size_t)sb * 2048;
  const char* wbase = (const char*)Wlds + (size_t)(wave * 16 + li) * 2048;
  const char* hbase = (const char*)Hs + (size_t)li * 2048;
  const int fxor = (li & 7) << 4;

  for (int t = 0; t < T_; ++t) {
    const unsigned etag = (unsigned)(ltag + t + 1);
    const unsigned long long pat =
        ((unsigned long long)etag << 48) | ((unsigned long long)etag << 16);
    const char* sbase = (const char*)h_ep +
        (((size_t)((t & 1) ^ 1) * B_ + gb * 16 + sb) * H_ + (size_t)seg * 64) * 4;

    // ---- speculative bulk read: all 32 u64 issued before any check (const indices)
    unsigned long long wv_[32];
#pragma unroll
    for (int p = 0; p < 16; ++p) {
      const int c = (p + seg) & 15;            // rotated chunk order (bank spread, addr-level)
      wv_[2 * p]     = ld_u64_cc(sbase + c * 16);
      wv_[2 * p + 1] = ld_u64_cc(sbase + c * 16 + 8);
    }
    // ---- validate + selective re-spin + pack to LDS (swizzled)
#pragma unroll
    for (int p = 0; p < 16; ++p) {
      const int c = (p + seg) & 15;
      unsigned long long a = wv_[2 * p], bq = wv_[2 * p + 1];
      while (((a ^ pat) & 0xFFFF0000FFFF0000ull) != 0ull) {
        __builtin_amdgcn_s_sleep(1);
        a = ld_u64_cc(sbase + c * 16);
      }
      while (((bq ^ pat) & 0xFFFF0000FFFF0000ull) != 0ull) {
        __builtin_amdgcn_s_sleep(1);
        bq = ld_u64_cc(sbase + c * 16 + 8);
      }
      const unsigned lo = ((unsigned)a & 0xffffu) | ((unsigned)(a >> 32) << 16);
      const unsigned hi = ((unsigned)bq & 0xffffu) | ((unsigned)(bq >> 32) << 16);
      *(unsigned long long*)(drow + ((seg * 128 + c * 8) ^ sswz)) =
          (unsigned long long)lo | ((unsigned long long)hi << 32);
    }
    __syncthreads();

    // ---- xv loads (consumed after MFMA; latency hides under it)
    float xv[4];
#pragma unroll
    for (int r = 0; r < 4; ++r)
      xv[r] = bf2f(xg[((size_t)b * T_ + t) * 4096 + r * 1024 + u]);

    // ---- MFMA: A=W(rows u*4+g), B=h(cols batch); 32 mfma, dual accumulators
    f32x4 acc0 = {0.f, 0.f, 0.f, 0.f}, acc1 = {0.f, 0.f, 0.f, 0.f};
#pragma unroll
    for (int ks = 0; ks < 32; ks += 2) {
      bf16x8 a0 = *(const bf16x8*)(wbase + ((ks * 64 + kq * 16) ^ fxor));
      bf16x8 b0 = *(const bf16x8*)(hbase + ((ks * 64 + kq * 16) ^ fxor));
      acc0 = __builtin_amdgcn_mfma_f32_16x16x32_bf16(a0, b0, acc0, 0, 0, 0);
      bf16x8 a1 = *(const bf16x8*)(wbase + (((ks + 1) * 64 + kq * 16) ^ fxor));
      bf16x8 b1 = *(const bf16x8*)(hbase + (((ks + 1) * 64 + kq * 16) ^ fxor));
      acc1 = __builtin_amdgcn_mfma_f32_16x16x32_bf16(a1, b1, acc1, 0, 0, 0);
    }

    // ---- lane-local cell update: regs r = gates i,f,g,o
    {
      float gi = acc0[0] + acc1[0] + xv[0];
      float gf = acc0[1] + acc1[1] + xv[1];
      float gg = acc0[2] + acc1[2] + xv[2];
      float go = acc0[3] + acc1[3] + xv[3];
      float ci = sigmf(gf) * c_st + sigmf(gi) * tanh_f(gg);
      c_st = ci;
      float h = sigmf(go) * tanh_f(ci);
      unsigned short hbf = f2bf(h);
      st_u32_cc(&h_ep[((size_t)(t & 1) * B_ + b) * H_ + u],
                ((etag + 1u) << 16) | (unsigned)hbf);
      asm volatile("s_waitcnt vmcnt(0)" ::: "memory");   // prompt visibility (R6 lesson)
      if (out_seq) out_seq[((size_t)b * T_ + t) * H_ + u] = hbf;   // deferred, fire-and-forget
      if (t == T_ - 1) {
        hT[(size_t)b * H_ + u] = h;
        cT[(size_t)b * H_ + u] = ci;
      }
    }
    __syncthreads();    // all Hs MFMA reads done before next stage overwrites
  }
}

// ---------------- launcher ----------------

extern "C" void kernel_launch(void* const* d_in, const int* in_sizes, int n_in,
                              void* d_out, int out_size, void* d_ws, size_t ws_size,
                              hipStream_t stream) {
  const float* seq  = (const float*)d_in[0];
  const float* Wi2h = (const float*)d_in[1];
  const float* bi2h = (const float*)d_in[2];
  const float* Wih  = (const float*)d_in[3];
  const float* Whh  = (const float*)d_in[4];
  const float* bih  = (const float*)d_in[5];
  const float* bhh  = (const float*)d_in[6];
  const float* Wh2o = (const float*)d_in[7];
  const float* bh2o = (const float*)d_in[8];
  const float* h0   = (const float*)d_in[9];
  const float* c0   = (const float*)d_in[10];
  float* outF = (float*)d_out;

  size_t off = 0;
  auto nb = [&](size_t bytes) { size_t r = off; off += (bytes + 255) & ~(size_t)255; return r; };
  unsigned short* xbf   = (unsigned short*)((char*)d_ws + nb((size_t)B_ * T_ * H_ * 2));
  unsigned short* seqA  = (unsigned short*)((char*)d_ws + nb((size_t)B_ * T_ * H_ * 2));
  unsigned short* xg    = (unsigned short*)((char*)d_ws + nb((size_t)B_ * T_ * 4 * H_ * 2));
  unsigned short* Wihb  = (unsigned short*)((char*)d_ws + nb((size_t)L_ * 4 * H_ * H_ * 2));
  unsigned short* Wh2ob = (unsigned short*)((char*)d_ws + nb((size_t)AS_ * H_ * 2));
  unsigned short* Wt    = (unsigned short*)((char*)d_ws + nb((size_t)AS_ * H_ * 2));
  float*          bsum  = (float*)((char*)d_ws + nb((size_t)L_ * 4 * H_ * 4));
  unsigned*       h_ep  = (unsigned*)((char*)d_ws + nb((size_t)2 * B_ * H_ * 4));  // 512KB
  (void)ws_size; (void)in_sizes; (void)n_in; (void)out_size;

  const int WLAYER = 4 * H_ * H_;

  k_wt_i2h<<<(AS_ * H_ + 255) / 256, 256, 0, stream>>>(Wi2h, bi2h, Wt);
  k_f2b<<<(L_ * WLAYER + 255) / 256, 256, 0, stream>>>(Wih, Wihb, L_ * WLAYER);
  k_f2b<<<(AS_ * H_ + 255) / 256, 256, 0, stream>>>(Wh2o, Wh2ob, AS_ * H_);
  k_bias<<<(L_ * 4 * H_ + 255) / 256, 256, 0, stream>>>(bih, bhh, bsum, L_ * 4 * H_);
  k_gather<<<B_ * T_, 128, 0, stream>>>(seq, Wt, xbf);

  // out = x @ W_h2O^T + b  (faithful to reference bug: uses x, not LSTM output)
  k_gemm<0><<<dim3(B_ * T_ / 128, AS_ / 128), 256, 0, stream>>>(
      xbf, Wh2ob, bh2o, (void*)outF, B_ * T_, AS_, H_);

  float* hT_base = outF + (size_t)B_ * T_ * AS_;
  float* cT_base = hT_base + (size_t)L_ * B_ * H_;

  for (int l = 0; l < L_; ++l) {
    const unsigned short* Ain = (l == 0) ? xbf : (l == 1) ? seqA : xbf;
    unsigned short* oseq = (l == 0) ? seqA : (l == 1) ? xbf : nullptr;
    k_gemm<1><<<dim3(B_ * T_ / 128, 4 * H_ / 128), 256, 0, stream>>>(
        Ain, Wihb + (size_t)l * WLAYER, bsum + (size_t)l * 4 * H_, (void*)xg,
        B_ * T_, 4 * H_, H_);
    k_scan<<<256, 256, 0, stream>>>(
        xg, Whh + (size_t)l * WLAYER, h_ep, oseq,
        hT_base + (size_t)l * B_ * H_, cT_base + (size_t)l * B_ * H_,
        h0 + (size_t)l * B_ * H_, c0 + (size_t)l * B_ * H_,
        l << 10);
  }
}

// Round 8
// 8781.538 us; speedup vs baseline: 1.7199x; 1.2317x over previous
//
#include <hip/hip_runtime.h>
#include <stdint.h>
#include <stddef.h>

#define B_  64
#define T_  256
#define H_  1024
#define AS_ 128
#define L_  3

typedef __attribute__((ext_vector_type(8))) short bf16x8;
typedef __attribute__((ext_vector_type(4))) float f32x4;

__device__ __forceinline__ unsigned short f2bf(float f) {
  union { float f; unsigned u; } x; x.f = f;
  unsigned r = x.u + 0x7fffu + ((x.u >> 16) & 1u);   // RNE
  return (unsigned short)(r >> 16);
}
__device__ __forceinline__ float bf2f(unsigned short s) {
  union { unsigned u; float f; } x; x.u = ((unsigned)s) << 16; return x.f;
}
__device__ __forceinline__ float sigmf(float x) { return 1.0f / (1.0f + __expf(-x)); }
__device__ __forceinline__ float tanh_f(float x) {
  x = fminf(fmaxf(x, -15.0f), 15.0f);
  float e = __expf(2.0f * x);
  return (e - 1.0f) / (e + 1.0f);
}

// ---- device-coherent (MALL) accessors: relaxed agent atomics — proven R2/R5 ----
__device__ __forceinline__ unsigned long long ld_u64_cc(const void* p) {
  return __hip_atomic_load((const unsigned long long*)p, __ATOMIC_RELAXED, __HIP_MEMORY_SCOPE_AGENT);
}
__device__ __forceinline__ void st_u32_cc(unsigned* p, unsigned v) {
  __hip_atomic_store(p, v, __ATOMIC_RELAXED, __HIP_MEMORY_SCOPE_AGENT);
}

// ---------------- tiny utility kernels ----------------

__global__ void k_wt_i2h(const float* __restrict__ W, const float* __restrict__ b,
                         unsigned short* __restrict__ Wt) {
  int id = blockIdx.x * 256 + threadIdx.x;
  if (id >= AS_ * H_) return;
  int a = id >> 10, h = id & 1023;
  Wt[id] = f2bf(W[h * AS_ + a] + b[h]);
}

__global__ void k_f2b(const float* __restrict__ s, unsigned short* __restrict__ d, int n) {
  int i = blockIdx.x * 256 + threadIdx.x;
  if (i < n) d[i] = f2bf(s[i]);
}

__global__ void k_bias(const float* __restrict__ bi, const float* __restrict__ bh,
                       float* __restrict__ o, int n) {
  int i = blockIdx.x * 256 + threadIdx.x;
  if (i < n) o[i] = bi[i] + bh[i];
}

__global__ __launch_bounds__(128) void k_gather(const float* __restrict__ seq,
                                                const unsigned short* __restrict__ Wt,
                                                unsigned short* __restrict__ xbf) {
  __shared__ int sidx;
  const int bt = blockIdx.x, tid = threadIdx.x;
  if (seq[(size_t)bt * AS_ + tid] > 0.5f) sidx = tid;
  __syncthreads();
  const uint4* s = (const uint4*)(Wt + (size_t)sidx * H_);
  uint4* d = (uint4*)(xbf + (size_t)bt * H_);
  d[tid] = s[tid];
}

// ---------------- MFMA GEMM ----------------
// OUT==0: float, row-major [M][N].  OUT==2: bf16 scan-native layout
// idx = ((t*4+gb)<<16) | (ug<<10) | (b_local<<6) | (u_local<<2) | gate
// derived from row = b*256+t (M=B*T), col = gate*1024+u (N=4096).

__device__ __forceinline__ void gld16(const void* g, void* l) {
  __builtin_amdgcn_global_load_lds((const __attribute__((address_space(1))) unsigned int*)g,
                                   (__attribute__((address_space(3))) unsigned int*)l,
                                   16, 0, 0);
}

template <int OUT>
__global__ __launch_bounds__(256) void k_gemm(const unsigned short* __restrict__ A,
                                              const unsigned short* __restrict__ Bm,
                                              const float* __restrict__ bias,
                                              void* __restrict__ Cout,
                                              int M, int N, int K) {
  __shared__ __align__(16) unsigned short As[128 * 32];
  __shared__ __align__(16) unsigned short Bs[128 * 32];
  const int tid = threadIdx.x, lane = tid & 63, wv = tid >> 6;
  const int m0 = blockIdx.x * 128, n0 = blockIdx.y * 128;
  const int wr = wv >> 1, wc = wv & 1;
  const int kg = lane >> 4, li = lane & 15;
  f32x4 acc[4][4] = {};

  for (int k0 = 0; k0 < K; k0 += 32) {
    for (int i = 0; i < 2; ++i) {
      int c0 = i * 256 + wv * 64;
      int cid = c0 + lane;
      int row = cid >> 2, lc = cid & 3;
      int sc = lc ^ ((row >> 1) & 3);
      gld16(A + (size_t)(m0 + row) * K + k0 + sc * 8, (char*)As + (size_t)c0 * 16);
      gld16(Bm + (size_t)(n0 + row) * K + k0 + sc * 8, (char*)Bs + (size_t)c0 * 16);
    }
    __syncthreads();
    bf16x8 af[4], bfm[4];
#pragma unroll
    for (int mi = 0; mi < 4; ++mi) {
      int row = wr * 64 + mi * 16 + li;
      int pc = kg ^ ((row >> 1) & 3);
      af[mi] = *(const bf16x8*)((const char*)As + row * 64 + pc * 16);
    }
#pragma unroll
    for (int ni = 0; ni < 4; ++ni) {
      int row = wc * 64 + ni * 16 + li;
      int pc = kg ^ ((row >> 1) & 3);
      bfm[ni] = *(const bf16x8*)((const char*)Bs + row * 64 + pc * 16);
    }
#pragma unroll
    for (int mi = 0; mi < 4; ++mi)
#pragma unroll
      for (int ni = 0; ni < 4; ++ni)
        acc[mi][ni] = __builtin_amdgcn_mfma_f32_16x16x32_bf16(af[mi], bfm[ni], acc[mi][ni], 0, 0, 0);
    __syncthreads();
  }

#pragma unroll
  for (int mi = 0; mi < 4; ++mi)
#pragma unroll
    for (int ni = 0; ni < 4; ++ni)
#pragma unroll
      for (int r = 0; r < 4; ++r) {
        int row = m0 + wr * 64 + mi * 16 + kg * 4 + r;
        int col = n0 + wc * 64 + ni * 16 + li;
        float v = acc[mi][ni][r] + bias[col];
        if (OUT == 0) {
          ((float*)Cout)[(size_t)row * N + col] = v;
        } else {
          int b = row >> 8, tt = row & 255;
          int g = col >> 10, u = col & 1023;
          int idx = ((tt * 4 + (b >> 4)) << 16) | ((u >> 4) << 10) |
                    ((b & 15) << 6) | ((u & 15) << 2) | g;
          ((unsigned short*)Cout)[idx] = f2bf(v);
        }
      }
}

// ---------------- persistent LSTM scan: batched-pass tagged dataflow ----------------
// h word = (tag<<16)|bf16 at parity t&1; tag = (l<<10)+t+2 (h0: tag (l<<10)+1, parity 1).
// Producer: one bypass u32 store + vmcnt(0) drain. Consumer: whole-slice batched read
// (32 u64 in flight, ONE wait) per pass; repeat until every tag matches (R7 lesson:
// never serialize per-word respins). No flags, no barriers between wgs; skew
// self-throttles to 1 step (write t+2 only after observing all of t+1, which
// data-depends on t consumed). Poison 0xAAAA never matches a tag; replays are
// bit-deterministic so stale-tag races are value-identical (benign).
// MFMA operand swap (proven R7): lane owns (batch=li, unit=ug*16+wave*4+kq),
// 4 acc regs = gates i,f,g,o — cell update lane-local.

__global__ __launch_bounds__(256, 1) void k_scan(
    const unsigned short* __restrict__ xgs,   // scan-native layout (see k_gemm OUT=2)
    const float* __restrict__ Whh,            // [4H][H] f32
    unsigned* __restrict__ h_ep,              // [2][B][H] u32 tagged (MALL)
    unsigned short* __restrict__ out_seq,     // [B*T][H] bf16 or null
    float* __restrict__ hT, float* __restrict__ cT,
    const float* __restrict__ h0, const float* __restrict__ c0,
    int ltag) {
  __shared__ __align__(16) unsigned short Wlds[64 * 1024];   // 128 KB
  __shared__ __align__(16) unsigned short Hs[16 * 1024];     // 32 KB  (total = 160 KB exactly)
  const int tid = threadIdx.x, lane = tid & 63, wave = tid >> 6;
  const int wg = blockIdx.x, gb = wg >> 6, ug = wg & 63;
  const int li = lane & 15, kq = lane >> 4;
  const int b  = gb * 16 + li;              // this thread's batch
  const int u  = ug * 16 + wave * 4 + kq;   // this thread's unit

  // ---- publish h0 first (visibility settles under the weight staging)
  st_u32_cc(&h_ep[((size_t)1 * B_ + b) * H_ + u],
            ((unsigned)(ltag + 1) << 16) | f2bf(h0[(size_t)b * H_ + u]));

  // ---- weights -> LDS: row rix holds W[gate=rix&3][ug*16 + (rix>>4)*4 + ((rix>>2)&3)]
  for (int it = 0; it < 64; ++it) {
    const float4 v4 = *(const float4*)&Whh[
        ((size_t)(it & 3) * H_ + ug * 16 + (it >> 4) * 4 + ((it >> 2) & 3)) * H_ + tid * 4];
    ushort4 p; p.x = f2bf(v4.x); p.y = f2bf(v4.y); p.z = f2bf(v4.z); p.w = f2bf(v4.w);
    *(ushort4*)((char*)Wlds + (size_t)it * 2048 + ((tid * 8) ^ ((it & 7) << 4))) = p;
  }
  float c_st = c0[(size_t)b * H_ + u];
  __syncthreads();

  const int sb = tid >> 4, seg = tid & 15;   // stage role: batch row sb, 64-unit segment seg
  const int sswz = (sb & 7) << 4;
  char* drow = (char*)Hs + (size_t)sb * 2048;
  const char* wbase = (const char*)Wlds + (size_t)(wave * 16 + li) * 2048;
  const char* hbase = (const char*)Hs + (size_t)li * 2048;
  const int fxor = (li & 7) << 4;

  for (int t = 0; t < T_; ++t) {
    const unsigned etag = (unsigned)(ltag + t + 1);
    const unsigned long long pat =
        ((unsigned long long)etag << 48) | ((unsigned long long)etag << 16);
    const char* sbase = (const char*)h_ep +
        (((size_t)((t & 1) ^ 1) * B_ + gb * 16 + sb) * H_ + (size_t)seg * 64) * 4;

    // xv: one aligned u64 (4 gates of (b,u)) from the scan-native xgs — coalesced
    const unsigned long long xvp = *(const unsigned long long*)(
        (const char*)xgs + ((((size_t)t * 4 + gb) << 16) | (ug << 10) | (li << 6) |
                            ((wave * 4 + kq) << 2)) * 2);

    // ---- batched-pass poll: all 32 u64 in flight per pass, one wait, full re-read
    unsigned long long w[32];
    for (;;) {
      bool ok;
      {
        unsigned long long bad = 0ull;
#pragma unroll
        for (int p = 0; p < 16; ++p) {
          const int c = (p + seg) & 15;            // rotated addresses (spread, static w-idx)
          w[2 * p]     = ld_u64_cc(sbase + c * 16);
          w[2 * p + 1] = ld_u64_cc(sbase + c * 16 + 8);
        }
#pragma unroll
        for (int m = 0; m < 32; ++m) bad |= (w[m] ^ pat) & 0xFFFF0000FFFF0000ull;
        ok = (bad == 0ull);
      }
      if (ok) break;
      __builtin_amdgcn_s_sleep(2);
    }
    // ---- pack + LDS write (swizzled; c-rotation also spreads banks)
#pragma unroll
    for (int p = 0; p < 16; ++p) {
      const int c = (p + seg) & 15;
      const unsigned lo = ((unsigned)w[2 * p] & 0xffffu) | ((unsigned)(w[2 * p] >> 32) << 16);
      const unsigned hi = ((unsigned)w[2 * p + 1] & 0xffffu) | ((unsigned)(w[2 * p + 1] >> 32) << 16);
      *(unsigned long long*)(drow + ((seg * 128 + c * 8) ^ sswz)) =
          (unsigned long long)lo | ((unsigned long long)hi << 32);
    }
    __syncthreads();                               // Hs ready

    // ---- MFMA: A=W rows (unit*4+gate), B=h cols (batch); dual accumulators
    f32x4 acc0 = {0.f, 0.f, 0.f, 0.f}, acc1 = {0.f, 0.f, 0.f, 0.f};
#pragma unroll
    for (int ks = 0; ks < 32; ks += 2) {
      bf16x8 a0 = *(const bf16x8*)(wbase + ((ks * 64 + kq * 16) ^ fxor));
      bf16x8 b0 = *(const bf16x8*)(hbase + ((ks * 64 + kq * 16) ^ fxor));
      acc0 = __builtin_amdgcn_mfma_f32_16x16x32_bf16(a0, b0, acc0, 0, 0, 0);
      bf16x8 a1 = *(const bf16x8*)(wbase + (((ks + 1) * 64 + kq * 16) ^ fxor));
      bf16x8 b1 = *(const bf16x8*)(hbase + (((ks + 1) * 64 + kq * 16) ^ fxor));
      acc1 = __builtin_amdgcn_mfma_f32_16x16x32_bf16(a1, b1, acc1, 0, 0, 0);
    }

    // ---- lane-local cell update; publish tagged h + drain (prompt visibility)
    unsigned hu;
    {
      const ushort4 xv = *(const ushort4*)&xvp;
      float gi = acc0[0] + acc1[0] + bf2f(xv.x);
      float gf = acc0[1] + acc1[1] + bf2f(xv.y);
      float gg = acc0[2] + acc1[2] + bf2f(xv.z);
      float go = acc0[3] + acc1[3] + bf2f(xv.w);
      float ci = sigmf(gf) * c_st + sigmf(gi) * tanh_f(gg);
      c_st = ci;
      float h = sigmf(go) * tanh_f(ci);
      unsigned short hbf = f2bf(h);
      hu = (unsigned)hbf;
      st_u32_cc(&h_ep[((size_t)(t & 1) * B_ + b) * H_ + u],
                ((etag + 1u) << 16) | hu);
      asm volatile("s_waitcnt vmcnt(0)" ::: "memory");
      if (t == T_ - 1) {
        hT[(size_t)b * H_ + u] = h;
        cT[(size_t)b * H_ + u] = ci;
      }
    }

    // ---- out_seq: shfl-pack 4 units -> u64, 8B stores from kq==0 lanes
    if (out_seq) {
      unsigned v0 = __shfl(hu, li);
      unsigned v1 = __shfl(hu, li + 16);
      unsigned v2 = __shfl(hu, li + 32);
      unsigned v3 = __shfl(hu, li + 48);
      if (kq == 0) {
        unsigned lo = (v0 & 0xffffu) | (v1 << 16);
        unsigned hi = (v2 & 0xffffu) | (v3 << 16);
        *(unsigned long long*)&out_seq[((size_t)b * T_ + t) * H_ + ug * 16 + wave * 4] =
            (unsigned long long)lo | ((unsigned long long)hi << 32);
      }
    }
    __syncthreads();                               // all Hs reads done before next stage
  }
}

// ---------------- launcher ----------------

extern "C" void kernel_launch(void* const* d_in, const int* in_sizes, int n_in,
                              void* d_out, int out_size, void* d_ws, size_t ws_size,
                              hipStream_t stream) {
  const float* seq  = (const float*)d_in[0];
  const float* Wi2h = (const float*)d_in[1];
  const float* bi2h = (const float*)d_in[2];
  const float* Wih  = (const float*)d_in[3];
  const float* Whh  = (const float*)d_in[4];
  const float* bih  = (const float*)d_in[5];
  const float* bhh  = (const float*)d_in[6];
  const float* Wh2o = (const float*)d_in[7];
  const float* bh2o = (const float*)d_in[8];
  const float* h0   = (const float*)d_in[9];
  const float* c0   = (const float*)d_in[10];
  float* outF = (float*)d_out;

  size_t off = 0;
  auto nb = [&](size_t bytes) { size_t r = off; off += (bytes + 255) & ~(size_t)255; return r; };
  unsigned short* xbf   = (unsigned short*)((char*)d_ws + nb((size_t)B_ * T_ * H_ * 2));
  unsigned short* seqA  = (unsigned short*)((char*)d_ws + nb((size_t)B_ * T_ * H_ * 2));
  unsigned short* xgs   = (unsigned short*)((char*)d_ws + nb((size_t)B_ * T_ * 4 * H_ * 2));
  unsigned short* Wihb  = (unsigned short*)((char*)d_ws + nb((size_t)L_ * 4 * H_ * H_ * 2));
  unsigned short* Wh2ob = (unsigned short*)((char*)d_ws + nb((size_t)AS_ * H_ * 2));
  unsigned short* Wt    = (unsigned short*)((char*)d_ws + nb((size_t)AS_ * H_ * 2));
  float*          bsum  = (float*)((char*)d_ws + nb((size_t)L_ * 4 * H_ * 4));
  unsigned*       h_ep  = (unsigned*)((char*)d_ws + nb((size_t)2 * B_ * H_ * 4));  // 512KB
  (void)ws_size; (void)in_sizes; (void)n_in; (void)out_size;

  const int WLAYER = 4 * H_ * H_;

  k_wt_i2h<<<(AS_ * H_ + 255) / 256, 256, 0, stream>>>(Wi2h, bi2h, Wt);
  k_f2b<<<(L_ * WLAYER + 255) / 256, 256, 0, stream>>>(Wih, Wihb, L_ * WLAYER);
  k_f2b<<<(AS_ * H_ + 255) / 256, 256, 0, stream>>>(Wh2o, Wh2ob, AS_ * H_);
  k_bias<<<(L_ * 4 * H_ + 255) / 256, 256, 0, stream>>>(bih, bhh, bsum, L_ * 4 * H_);
  k_gather<<<B_ * T_, 128, 0, stream>>>(seq, Wt, xbf);

  // out = x @ W_h2O^T + b  (faithful to reference bug: uses x, not LSTM output)
  k_gemm<0><<<dim3(B_ * T_ / 128, AS_ / 128), 256, 0, stream>>>(
      xbf, Wh2ob, bh2o, (void*)outF, B_ * T_, AS_, H_);

  float* hT_base = outF + (size_t)B_ * T_ * AS_;
  float* cT_base = hT_base + (size_t)L_ * B_ * H_;

  for (int l = 0; l < L_; ++l) {
    const unsigned short* Ain = (l == 0) ? xbf : (l == 1) ? seqA : xbf;
    unsigned short* oseq = (l == 0) ? seqA : (l == 1) ? xbf : nullptr;
    k_gemm<2><<<dim3(B_ * T_ / 128, 4 * H_ / 128), 256, 0, stream>>>(
        Ain, Wihb + (size_t)l * WLAYER, bsum + (size_t)l * 4 * H_, (void*)xgs,
        B_ * T_, 4 * H_, H_);
    k_scan<<<256, 256, 0, stream>>>(
        xgs, Whh + (size_t)l * WLAYER, h_ep, oseq,
        hT_base + (size_t)l * B_ * H_, cT_base + (size_t)l * B_ * H_,
        h0 + (size_t)l * B_ * H_, c0 + (size_t)l * B_ * H_,
        l << 10);
  }
}

// Round 9
// 5384.958 us; speedup vs baseline: 2.8047x; 1.6308x over previous
//
#include <hip/hip_runtime.h>
#include <stdint.h>
#include <stddef.h>

#define B_  64
#define T_  256
#define H_  1024
#define AS_ 128
#define L_  3

typedef __attribute__((ext_vector_type(8))) short bf16x8;
typedef __attribute__((ext_vector_type(4))) float f32x4;

__device__ __forceinline__ unsigned short f2bf(float f) {
  union { float f; unsigned u; } x; x.f = f;
  unsigned r = x.u + 0x7fffu + ((x.u >> 16) & 1u);   // RNE
  return (unsigned short)(r >> 16);
}
__device__ __forceinline__ float bf2f(unsigned short s) {
  union { unsigned u; float f; } x; x.u = ((unsigned)s) << 16; return x.f;
}
__device__ __forceinline__ float sigmf(float x) { return 1.0f / (1.0f + __expf(-x)); }
__device__ __forceinline__ float tanh_f(float x) {
  x = fminf(fmaxf(x, -15.0f), 15.0f);
  float e = __expf(2.0f * x);
  return (e - 1.0f) / (e + 1.0f);
}

// ---- device-coherent (MALL) accessors: relaxed agent atomics — proven R2/R5/R8 ----
__device__ __forceinline__ unsigned long long ld_u64_cc(const void* p) {
  return __hip_atomic_load((const unsigned long long*)p, __ATOMIC_RELAXED, __HIP_MEMORY_SCOPE_AGENT);
}
__device__ __forceinline__ void st_u16_cc(unsigned short* p, unsigned short v) {
  __hip_atomic_store(p, v, __ATOMIC_RELAXED, __HIP_MEMORY_SCOPE_AGENT);
}
__device__ __forceinline__ void st_u32_cc(unsigned* p, unsigned v) {
  __hip_atomic_store(p, v, __ATOMIC_RELAXED, __HIP_MEMORY_SCOPE_AGENT);
}
__device__ __forceinline__ unsigned ld_u32_cc(const unsigned* p) {
  return __hip_atomic_load(p, __ATOMIC_RELAXED, __HIP_MEMORY_SCOPE_AGENT);
}

// ---------------- tiny utility kernels ----------------

__global__ void k_zero(unsigned* p, int n) {
  int i = blockIdx.x * 256 + threadIdx.x;
  if (i < n) st_u32_cc(p + i, 0u);
}

__global__ void k_wt_i2h(const float* __restrict__ W, const float* __restrict__ b,
                         unsigned short* __restrict__ Wt) {
  int id = blockIdx.x * 256 + threadIdx.x;
  if (id >= AS_ * H_) return;
  int a = id >> 10, h = id & 1023;
  Wt[id] = f2bf(W[h * AS_ + a] + b[h]);
}

__global__ void k_f2b(const float* __restrict__ s, unsigned short* __restrict__ d, int n) {
  int i = blockIdx.x * 256 + threadIdx.x;
  if (i < n) d[i] = f2bf(s[i]);
}

__global__ void k_bias(const float* __restrict__ bi, const float* __restrict__ bh,
                       float* __restrict__ o, int n) {
  int i = blockIdx.x * 256 + threadIdx.x;
  if (i < n) o[i] = bi[i] + bh[i];
}

__global__ __launch_bounds__(128) void k_gather(const float* __restrict__ seq,
                                                const unsigned short* __restrict__ Wt,
                                                unsigned short* __restrict__ xbf) {
  __shared__ int sidx;
  const int bt = blockIdx.x, tid = threadIdx.x;
  if (seq[(size_t)bt * AS_ + tid] > 0.5f) sidx = tid;
  __syncthreads();
  const uint4* s = (const uint4*)(Wt + (size_t)sidx * H_);
  uint4* d = (uint4*)(xbf + (size_t)bt * H_);
  d[tid] = s[tid];
}

// ---------------- MFMA GEMM ----------------
// OUT==0: float row-major [M][N].  OUT==2: bf16 scan-native (uu=32) layout:
// idx = ((t*4+gb)<<16) | (ug<<11) | (b_local<<7) | (u_local<<2) | gate
// from row = b*256+t (M=B*T), col = gate*1024+u (N=4096); ug=u>>5, u_local=u&31.

__device__ __forceinline__ void gld16(const void* g, void* l) {
  __builtin_amdgcn_global_load_lds((const __attribute__((address_space(1))) unsigned int*)g,
                                   (__attribute__((address_space(3))) unsigned int*)l,
                                   16, 0, 0);
}

template <int OUT>
__global__ __launch_bounds__(256) void k_gemm(const unsigned short* __restrict__ A,
                                              const unsigned short* __restrict__ Bm,
                                              const float* __restrict__ bias,
                                              void* __restrict__ Cout,
                                              int M, int N, int K) {
  __shared__ __align__(16) unsigned short As[128 * 32];
  __shared__ __align__(16) unsigned short Bs[128 * 32];
  const int tid = threadIdx.x, lane = tid & 63, wv = tid >> 6;
  const int m0 = blockIdx.x * 128, n0 = blockIdx.y * 128;
  const int wr = wv >> 1, wc = wv & 1;
  const int kg = lane >> 4, li = lane & 15;
  f32x4 acc[4][4] = {};

  for (int k0 = 0; k0 < K; k0 += 32) {
    for (int i = 0; i < 2; ++i) {
      int c0 = i * 256 + wv * 64;
      int cid = c0 + lane;
      int row = cid >> 2, lc = cid & 3;
      int sc = lc ^ ((row >> 1) & 3);
      gld16(A + (size_t)(m0 + row) * K + k0 + sc * 8, (char*)As + (size_t)c0 * 16);
      gld16(Bm + (size_t)(n0 + row) * K + k0 + sc * 8, (char*)Bs + (size_t)c0 * 16);
    }
    __syncthreads();
    bf16x8 af[4], bfm[4];
#pragma unroll
    for (int mi = 0; mi < 4; ++mi) {
      int row = wr * 64 + mi * 16 + li;
      int pc = kg ^ ((row >> 1) & 3);
      af[mi] = *(const bf16x8*)((const char*)As + row * 64 + pc * 16);
    }
#pragma unroll
    for (int ni = 0; ni < 4; ++ni) {
      int row = wc * 64 + ni * 16 + li;
      int pc = kg ^ ((row >> 1) & 3);
      bfm[ni] = *(const bf16x8*)((const char*)Bs + row * 64 + pc * 16);
    }
#pragma unroll
    for (int mi = 0; mi < 4; ++mi)
#pragma unroll
      for (int ni = 0; ni < 4; ++ni)
        acc[mi][ni] = __builtin_amdgcn_mfma_f32_16x16x32_bf16(af[mi], bfm[ni], acc[mi][ni], 0, 0, 0);
    __syncthreads();
  }

#pragma unroll
  for (int mi = 0; mi < 4; ++mi)
#pragma unroll
    for (int ni = 0; ni < 4; ++ni)
#pragma unroll
      for (int r = 0; r < 4; ++r) {
        int row = m0 + wr * 64 + mi * 16 + kg * 4 + r;
        int col = n0 + wc * 64 + ni * 16 + li;
        float v = acc[mi][ni][r] + bias[col];
        if (OUT == 0) {
          ((float*)Cout)[(size_t)row * N + col] = v;
        } else {
          int b = row >> 8, tt = row & 255;
          int g = col >> 10, u = col & 1023;
          int idx = ((tt * 4 + (b >> 4)) << 16) | ((u >> 5) << 11) |
                    ((b & 15) << 7) | ((u & 31) << 2) | g;
          ((unsigned short*)Cout)[idx] = f2bf(v);
        }
      }
}

// ---------------- persistent LSTM scan: uu=32, weights in VGPR+LDS, slot signaling ----------------
// 128 wgs: wg = (gb in [0,4), ug in [0,32)) owns batches [gb*16,+16) x units [ug*32,+32).
// Weight rows r = u_local*4+gate (128 rows): rows [w*32,+16) per wave in 128 VGPRs
// (loop-invariant A-fragments!), rows [w*32+16,+16) in LDS (128KB). h stage 32KB. =160KB.
// Signal: slot[gb][ug] = publishes done (h0->1, step t->t+2), bypass store after drain.
// Consumer: poll 32 slots (one 128B coalesced read/pass) >= t+1, then ONE untagged
// bulk read (16 u64/thread). Total uncached bulk: 4 MB/step (was 8-16).
// Overwrite safety: slot>=t+1 for all ug => every wg consumed the parity about
// to be overwritten (its publish data-depends on that read). Skew <= 1 step.

__global__ __launch_bounds__(256, 1) void k_scan(
    const unsigned short* __restrict__ xgs,   // scan-native (see k_gemm OUT=2)
    const float* __restrict__ Whh,            // [4H][H] f32
    unsigned short* __restrict__ h_pp,        // [2][B][H] bf16 (MALL)
    unsigned short* __restrict__ out_seq,     // [B*T][H] bf16 or null
    float* __restrict__ hT, float* __restrict__ cT,
    const float* __restrict__ h0, const float* __restrict__ c0,
    unsigned* __restrict__ slots) {           // [4][32] this layer
  __shared__ __align__(16) unsigned short Wlds[64 * 1024];   // 128 KB
  __shared__ __align__(16) unsigned short Hs[16 * 1024];     // 32 KB
  const int tid = threadIdx.x, lane = tid & 63, w = tid >> 6;
  const int gb = blockIdx.x >> 5, ug = blockIdx.x & 31;
  const int li = lane & 15, kq = lane >> 4;
  const int b  = gb * 16 + li;
  const int u0 = ug * 32 + w * 8 + kq;        // acc0's unit
  const int u1 = u0 + 4;                      // acc1's unit

  // ---- publish h0 (read parity 1 at t=0)
  st_u16_cc(&h_pp[((size_t)B_ + b) * H_ + u0], f2bf(h0[(size_t)b * H_ + u0]));
  st_u16_cc(&h_pp[((size_t)B_ + b) * H_ + u1], f2bf(h0[(size_t)b * H_ + u1]));

  // ---- register A-fragments: tile rows r0 = w*32+li, all K (loop-invariant)
  bf16x8 afr[32];
  {
    const int r0 = w * 32 + li;               // u_local = r0>>2, gate = r0&3
    const float* wr = Whh + ((size_t)(r0 & 3) * H_ + ug * 32 + (r0 >> 2)) * H_ + kq * 8;
#pragma unroll
    for (int ks = 0; ks < 32; ++ks) {
      const float4 f0 = *(const float4*)(wr + ks * 32);
      const float4 f1 = *(const float4*)(wr + ks * 32 + 4);
      union { ushort4 a[2]; bf16x8 v; } uu_;
      uu_.a[0] = ushort4{f2bf(f0.x), f2bf(f0.y), f2bf(f0.z), f2bf(f0.w)};
      uu_.a[1] = ushort4{f2bf(f1.x), f2bf(f1.y), f2bf(f1.z), f2bf(f1.w)};
      afr[ks] = uu_.v;
    }
  }
  // ---- LDS A tile: rows r = w*32+16+it -> LDS row w*16+it (XOR swizzle by it&7)
  for (int it = 0; it < 16; ++it) {
    const int r = w * 32 + 16 + it;
    const float* wr = Whh + ((size_t)(r & 3) * H_ + ug * 32 + (r >> 2)) * H_;
#pragma unroll
    for (int j = 0; j < 4; ++j) {
      const float4 f = *(const float4*)(wr + lane * 16 + j * 4);
      ushort4 p = ushort4{f2bf(f.x), f2bf(f.y), f2bf(f.z), f2bf(f.w)};
      const int k = lane * 16 + j * 4;
      *(ushort4*)((char*)Wlds + (size_t)(w * 16 + it) * 2048 + ((2 * k) ^ ((it & 7) << 4))) = p;
    }
  }
  float cs0 = c0[(size_t)b * H_ + u0], cs1 = c0[(size_t)b * H_ + u1];
  __syncthreads();                            // drains h0 stores (per-wave vmcnt0)
  unsigned* slmy = slots + gb * 32 + ug;
  if (tid == 0) {
    st_u32_cc(slmy, 1u);
    asm volatile("s_waitcnt vmcnt(0)" ::: "memory");
  }

  const char* hbase = (const char*)Hs + (size_t)li * 2048;
  const char* wlb   = (const char*)Wlds + (size_t)(w * 16 + li) * 2048;
  const int fxor = (li & 7) << 4;
  const int sb = tid >> 4, seg = tid & 15;
  const int sswz = (sb & 7) << 4;
  char* drow = (char*)Hs + (size_t)sb * 2048;
  const unsigned* sl = slots + gb * 32;

  for (int t = 0; t < T_; ++t) {
    // ---- poll the 32 slots (one 128B coalesced read per pass)
    if (w == 0) {
      const unsigned tgt = (unsigned)(t + 1);
      unsigned v;
      do {
        __builtin_amdgcn_s_sleep(1);
        v = ld_u32_cc(&sl[lane & 31]);
      } while (__any((int)(v < tgt)));
    }
    __syncthreads();

    // ---- ONE untagged bulk read (16 u64/thread, rotated) -> LDS swizzled
    {
      const char* src = (const char*)(h_pp + (size_t)((t & 1) ^ 1) * (B_ * H_) +
                                      (size_t)(gb * 16 + sb) * H_) + seg * 128;
      unsigned long long wb[16];
#pragma unroll
      for (int p = 0; p < 16; ++p) wb[p] = ld_u64_cc(src + ((p + seg) & 15) * 8);
#pragma unroll
      for (int p = 0; p < 16; ++p) {
        const int c = (p + seg) & 15;
        *(unsigned long long*)(drow + ((seg * 128 + c * 8) ^ sswz)) = wb[p];
      }
    }
    // ---- xv: two u64s (4 gates each for u0,u1), coalesced scan-native layout
    const size_t xb2 = ((((size_t)t * 4 + gb) << 16) | (ug << 11) | (li << 7) |
                        ((w * 8 + kq) << 2)) * 2;
    const ushort4 xa = *(const ushort4*)((const char*)xgs + xb2);
    const ushort4 xb = *(const ushort4*)((const char*)xgs + xb2 + 32);
    __syncthreads();                          // Hs staged

    // ---- MFMA: one h B-frag feeds reg-A (acc0) and LDS-A (acc1)
    f32x4 a0 = {0.f, 0.f, 0.f, 0.f}, a1 = {0.f, 0.f, 0.f, 0.f};
#pragma unroll
    for (int ks = 0; ks < 32; ++ks) {
      const bf16x8 bb = *(const bf16x8*)(hbase + ((ks * 64 + kq * 16) ^ fxor));
      a0 = __builtin_amdgcn_mfma_f32_16x16x32_bf16(afr[ks], bb, a0, 0, 0, 0);
      const bf16x8 aw = *(const bf16x8*)(wlb + ((ks * 64 + kq * 16) ^ fxor));
      a1 = __builtin_amdgcn_mfma_f32_16x16x32_bf16(aw, bb, a1, 0, 0, 0);
    }

    // ---- lane-local cell update (2 units x 4 gates)
    float h0v, h1v;
    {
      float gi = a0[0] + bf2f(xa.x), gf = a0[1] + bf2f(xa.y);
      float gg = a0[2] + bf2f(xa.z), go = a0[3] + bf2f(xa.w);
      float ci = sigmf(gf) * cs0 + sigmf(gi) * tanh_f(gg);
      cs0 = ci; h0v = sigmf(go) * tanh_f(ci);
    }
    {
      float gi = a1[0] + bf2f(xb.x), gf = a1[1] + bf2f(xb.y);
      float gg = a1[2] + bf2f(xb.z), go = a1[3] + bf2f(xb.w);
      float ci = sigmf(gf) * cs1 + sigmf(gi) * tanh_f(gg);
      cs1 = ci; h1v = sigmf(go) * tanh_f(ci);
    }
    const unsigned short hb0 = f2bf(h0v), hb1 = f2bf(h1v);
    if (out_seq) {
      out_seq[((size_t)b * T_ + t) * H_ + u0] = hb0;
      out_seq[((size_t)b * T_ + t) * H_ + u1] = hb1;
    }
    if (t < T_ - 1) {
      st_u16_cc(&h_pp[((size_t)(t & 1) * B_ + b) * H_ + u0], hb0);
      st_u16_cc(&h_pp[((size_t)(t & 1) * B_ + b) * H_ + u1], hb1);
      __syncthreads();                        // all waves' publishes drained
      if (tid == 0) {
        st_u32_cc(slmy, (unsigned)(t + 2));
        asm volatile("s_waitcnt vmcnt(0)" ::: "memory");
      }
    } else {
      hT[(size_t)b * H_ + u0] = h0v; hT[(size_t)b * H_ + u1] = h1v;
      cT[(size_t)b * H_ + u0] = cs0; cT[(size_t)b * H_ + u1] = cs1;
    }
  }
}

// ---------------- launcher ----------------

extern "C" void kernel_launch(void* const* d_in, const int* in_sizes, int n_in,
                              void* d_out, int out_size, void* d_ws, size_t ws_size,
                              hipStream_t stream) {
  const float* seq  = (const float*)d_in[0];
  const float* Wi2h = (const float*)d_in[1];
  const float* bi2h = (const float*)d_in[2];
  const float* Wih  = (const float*)d_in[3];
  const float* Whh  = (const float*)d_in[4];
  const float* bih  = (const float*)d_in[5];
  const float* bhh  = (const float*)d_in[6];
  const float* Wh2o = (const float*)d_in[7];
  const float* bh2o = (const float*)d_in[8];
  const float* h0   = (const float*)d_in[9];
  const float* c0   = (const float*)d_in[10];
  float* outF = (float*)d_out;

  size_t off = 0;
  auto nb = [&](size_t bytes) { size_t r = off; off += (bytes + 255) & ~(size_t)255; return r; };
  unsigned short* xbf   = (unsigned short*)((char*)d_ws + nb((size_t)B_ * T_ * H_ * 2));
  unsigned short* seqA  = (unsigned short*)((char*)d_ws + nb((size_t)B_ * T_ * H_ * 2));
  unsigned short* xgs   = (unsigned short*)((char*)d_ws + nb((size_t)B_ * T_ * 4 * H_ * 2));
  unsigned short* Wihb  = (unsigned short*)((char*)d_ws + nb((size_t)L_ * 4 * H_ * H_ * 2));
  unsigned short* Wh2ob = (unsigned short*)((char*)d_ws + nb((size_t)AS_ * H_ * 2));
  unsigned short* Wt    = (unsigned short*)((char*)d_ws + nb((size_t)AS_ * H_ * 2));
  float*          bsum  = (float*)((char*)d_ws + nb((size_t)L_ * 4 * H_ * 4));
  unsigned short* h_pp  = (unsigned short*)((char*)d_ws + nb((size_t)2 * B_ * H_ * 2));  // 256KB
  unsigned*       slt   = (unsigned*)((char*)d_ws + nb((size_t)L_ * 128 * 4));
  (void)ws_size; (void)in_sizes; (void)n_in; (void)out_size;

  const int WLAYER = 4 * H_ * H_;

  k_zero<<<2, 256, 0, stream>>>(slt, L_ * 128);
  k_wt_i2h<<<(AS_ * H_ + 255) / 256, 256, 0, stream>>>(Wi2h, bi2h, Wt);
  k_f2b<<<(L_ * WLAYER + 255) / 256, 256, 0, stream>>>(Wih, Wihb, L_ * WLAYER);
  k_f2b<<<(AS_ * H_ + 255) / 256, 256, 0, stream>>>(Wh2o, Wh2ob, AS_ * H_);
  k_bias<<<(L_ * 4 * H_ + 255) / 256, 256, 0, stream>>>(bih, bhh, bsum, L_ * 4 * H_);
  k_gather<<<B_ * T_, 128, 0, stream>>>(seq, Wt, xbf);

  // out = x @ W_h2O^T + b  (faithful to reference bug: uses x, not LSTM output)
  k_gemm<0><<<dim3(B_ * T_ / 128, AS_ / 128), 256, 0, stream>>>(
      xbf, Wh2ob, bh2o, (void*)outF, B_ * T_, AS_, H_);

  float* hT_base = outF + (size_t)B_ * T_ * AS_;
  float* cT_base = hT_base + (size_t)L_ * B_ * H_;

  for (int l = 0; l < L_; ++l) {
    const unsigned short* Ain = (l == 0) ? xbf : (l == 1) ? seqA : xbf;
    unsigned short* oseq = (l == 0) ? seqA : (l == 1) ? xbf : nullptr;
    k_gemm<2><<<dim3(B_ * T_ / 128, 4 * H_ / 128), 256, 0, stream>>>(
        Ain, Wihb + (size_t)l * WLAYER, bsum + (size_t)l * 4 * H_, (void*)xgs,
        B_ * T_, 4 * H_, H_);
    k_scan<<<128, 256, 0, stream>>>(
        xgs, Whh + (size_t)l * WLAYER, h_pp, oseq,
        hT_base + (size_t)l * B_ * H_, cT_base + (size_t)l * B_ * H_,
        h0 + (size_t)l * B_ * H_, c0 + (size_t)l * B_ * H_,
        slt + (size_t)l * 128);
  }
}